// Round 2
// baseline (378.803 us; speedup 1.0000x reference)
//
#include <hip/hip_runtime.h>
#include <cfloat>
#include <math.h>

#define NPTS   5000
#define BATCH  2
#define DIM    128
#define NBINS  10
#define BINSZ  500
#define TOPK   5
#define ROTCOLS 100   // rotations stored [128, 100]; we use first NBINS/2 = 5

// ---------------- Kernel A: bin assignment + squared norms (fp64 acc) -----
__global__ void k_bins(const float* __restrict__ pts, const float* __restrict__ rot,
                       int* __restrict__ bin_idx, double* __restrict__ na) {
    __shared__ float rotL[DIM * 5];
    int tid = threadIdx.x;
    for (int f = tid; f < DIM * 5; f += blockDim.x)
        rotL[f] = rot[(f / 5) * ROTCOLS + (f % 5)];
    __syncthreads();

    int i = blockIdx.x * blockDim.x + tid;
    if (i >= BATCH * NPTS) return;

    double acc[5] = {0., 0., 0., 0., 0.};
    double sq = 0.;
    const float* p = pts + (size_t)i * DIM;
    for (int d = 0; d < DIM; ++d) {
        double v = (double)p[d];
        sq += v * v;
#pragma unroll
        for (int h = 0; h < 5; ++h) acc[h] += v * (double)rotL[d * 5 + h];
    }
    // argmax over [acc0..4, -acc0..4], first-occurrence wins (strict >)
    double best = acc[0]; int bc = 0;
#pragma unroll
    for (int c = 1; c < NBINS; ++c) {
        double v = (c < 5) ? acc[c] : -acc[c - 5];
        if (v > best) { best = v; bc = c; }
    }
    bin_idx[i] = bc;
    na[i] = sq;
}

// ---------------- Kernel B: stable counting sort (== stable argsort) ------
__global__ void k_sort(const int* __restrict__ bin_idx, int* __restrict__ order) {
    const int b = blockIdx.x;
    const int t = threadIdx.x;               // 256 threads
    const int NPT = (NPTS + 255) / 256;      // 20
    int start = t * NPT;
    int end   = min(NPTS, start + NPT);

    int cnt[NBINS];
#pragma unroll
    for (int c = 0; c < NBINS; ++c) cnt[c] = 0;
    for (int i = start; i < end; ++i) cnt[bin_idx[b * NPTS + i]]++;

    __shared__ int hist[NBINS * 256];        // bin-major: hist[c*256 + t]
#pragma unroll
    for (int c = 0; c < NBINS; ++c) hist[c * 256 + t] = cnt[c];
    __syncthreads();

    // exclusive scan over flat bin-major array (2560): thread t owns flat [t*10, t*10+10)
    int base = t * NBINS;
    int s = 0;
#pragma unroll
    for (int k = 0; k < NBINS; ++k) s += hist[base + k];
    __shared__ int scan[256];
    scan[t] = s;
    __syncthreads();
    for (int off = 1; off < 256; off <<= 1) {
        int v = (t >= off) ? scan[t - off] : 0;
        __syncthreads();
        scan[t] += v;
        __syncthreads();
    }
    int run = scan[t] - s;                   // exclusive prefix at flat idx t*NBINS
#pragma unroll
    for (int k = 0; k < NBINS; ++k) { int h = hist[base + k]; hist[base + k] = run; run += h; }
    __syncthreads();

    int ofs[NBINS];
#pragma unroll
    for (int c = 0; c < NBINS; ++c) ofs[c] = hist[c * 256 + t];
    for (int i = start; i < end; ++i) {
        int c = bin_idx[b * NPTS + i];
        order[b * NPTS + ofs[c]] = i;        // stable: bin-major, thread-major, index-major
        ofs[c]++;
    }
}

// ---------------- Kernel C: per-chunk gram + top-5 + scatter (fp64) -------
#define RT    64       // rows per block
#define CTILE 64       // cols per LDS tile
#define RSTR  132      // padded row stride in floats (2-way LDS aliasing only, free)
#define NCT   8        // ceil(500/64)
#define CANDW 81       // padded candidate row

__launch_bounds__(256)
__global__ void k_chunks(const float* __restrict__ pts, const double* __restrict__ na,
                         const int* __restrict__ order, float* __restrict__ out) {
    __shared__ float  rowP[RT * RSTR];
    __shared__ float  colP[CTILE * RSTR];
    __shared__ double naC[CTILE];
    __shared__ double naRs[RT];
    __shared__ int    ordR[RT];
    __shared__ double candV[RT * CANDW];
    __shared__ int    candL[RT * CANDW];

    int blk   = blockIdx.x;
    int rt    = blk & 7;
    int chunk = blk >> 3;          // 0..19
    int b     = chunk / NBINS;
    int c     = chunk % NBINS;
    int tid   = threadIdx.x;
    int row0  = rt * RT;
    int rowCount = min(RT, BINSZ - row0);

    const int*   ordBase = order + b * NPTS + c * BINSZ;
    const float* ptsB    = pts + (size_t)b * NPTS * DIM;

    // stage row points (gathered via order)
    for (int f = tid; f < rowCount * (DIM / 4); f += 256) {
        int r = f / (DIM / 4);
        int q = f % (DIM / 4);
        int g = ordBase[row0 + r];
        float4 v = *(const float4*)(ptsB + (size_t)g * DIM + q * 4);
        *(float4*)(&rowP[r * RSTR + q * 4]) = v;
    }
    if (tid < rowCount) {
        int g = ordBase[row0 + tid];
        ordR[tid] = g;
        naRs[tid] = na[b * NPTS + g];
    }
    __syncthreads();

    int rg = tid >> 4;   // 0..15 -> rows rg + 16*ii
    int cg = tid & 15;   // 0..15 -> cols cg + 16*jj

    double naRr[4];
#pragma unroll
    for (int ii = 0; ii < 4; ++ii) {
        int r = rg + 16 * ii;
        naRr[ii] = (r < rowCount) ? naRs[r] : 0.;
    }

    double tv[4][TOPK];
    int    tl[4][TOPK];
#pragma unroll
    for (int ii = 0; ii < 4; ++ii)
#pragma unroll
        for (int k = 0; k < TOPK; ++k) { tv[ii][k] = -DBL_MAX; tl[ii][k] = 0x7fffffff; }

    for (int ct = 0; ct < NCT; ++ct) {
        int col0 = ct * CTILE;
        int colCount = min(CTILE, BINSZ - col0);
        __syncthreads();   // previous tile's readers done before restage
        for (int f = tid; f < colCount * (DIM / 4); f += 256) {
            int j = f / (DIM / 4);
            int q = f % (DIM / 4);
            int g = ordBase[col0 + j];
            float4 v = *(const float4*)(ptsB + (size_t)g * DIM + q * 4);
            *(float4*)(&colP[j * RSTR + q * 4]) = v;
        }
        if (tid < colCount) {
            int g = ordBase[col0 + tid];
            naC[tid] = na[b * NPTS + g];
        }
        __syncthreads();

        double acc[4][4];
#pragma unroll
        for (int ii = 0; ii < 4; ++ii)
#pragma unroll
            for (int jj = 0; jj < 4; ++jj) acc[ii][jj] = 0.;

        const float4* rowP4 = (const float4*)rowP;
        const float4* colP4 = (const float4*)colP;
        for (int q = 0; q < DIM / 4; ++q) {
            float4 a[4], bb[4];
#pragma unroll
            for (int ii = 0; ii < 4; ++ii) a[ii] = rowP4[(rg + 16 * ii) * (RSTR / 4) + q];
#pragma unroll
            for (int jj = 0; jj < 4; ++jj) bb[jj] = colP4[(cg + 16 * jj) * (RSTR / 4) + q];
            double ad[4][4], bd[4][4];
#pragma unroll
            for (int ii = 0; ii < 4; ++ii) {
                ad[ii][0] = (double)a[ii].x; ad[ii][1] = (double)a[ii].y;
                ad[ii][2] = (double)a[ii].z; ad[ii][3] = (double)a[ii].w;
            }
#pragma unroll
            for (int jj = 0; jj < 4; ++jj) {
                bd[jj][0] = (double)bb[jj].x; bd[jj][1] = (double)bb[jj].y;
                bd[jj][2] = (double)bb[jj].z; bd[jj][3] = (double)bb[jj].w;
            }
#pragma unroll
            for (int ii = 0; ii < 4; ++ii)
#pragma unroll
                for (int jj = 0; jj < 4; ++jj)
                    acc[ii][jj] += ad[ii][0] * bd[jj][0] + ad[ii][1] * bd[jj][1]
                                 + ad[ii][2] * bd[jj][2] + ad[ii][3] * bd[jj][3];
        }

        // dm + per-thread running top-5 (candidates arrive in increasing local idx)
#pragma unroll
        for (int jj = 0; jj < 4; ++jj) {
            int j = cg + 16 * jj;
            if (j < colCount) {
                int lc = col0 + j;
                double nc = naC[j];
#pragma unroll
                for (int ii = 0; ii < 4; ++ii) {
                    double d2   = naRr[ii] + nc - 2. * acc[ii][jj];
                    double dist = sqrt(fmax(d2, 1e-6));
                    double cv   = exp(-0.1 * dist);
                    int    cl   = lc;
#pragma unroll
                    for (int k = 0; k < TOPK; ++k) {   // strict > : equal keeps earlier idx
                        bool gt = (cv > tv[ii][k]);
                        double ov = tv[ii][k]; int ol = tl[ii][k];
                        if (gt) { tv[ii][k] = cv; tl[ii][k] = cl; cv = ov; cl = ol; }
                    }
                }
            }
        }
    }

    // merge 16 column-group threads' top-5 per row
    __syncthreads();
#pragma unroll
    for (int ii = 0; ii < 4; ++ii) {
        int r = rg + 16 * ii;
#pragma unroll
        for (int k = 0; k < TOPK; ++k) {
            candV[r * CANDW + cg * TOPK + k] = tv[ii][k];
            candL[r * CANDW + cg * TOPK + k] = tl[ii][k];
        }
    }
    __syncthreads();

    if (tid < rowCount) {
        int r = tid;
        double bv[TOPK]; int bl[TOPK];
#pragma unroll
        for (int k = 0; k < TOPK; ++k) { bv[k] = -DBL_MAX; bl[k] = 0x7fffffff; }
        for (int m = 0; m < 16 * TOPK; ++m) {
            double cv = candV[r * CANDW + m];
            int    cl = candL[r * CANDW + m];
#pragma unroll
            for (int k = 0; k < TOPK; ++k) {   // (val desc, idx asc) total order
                bool better = (cv > bv[k]) || (cv == bv[k] && cl < bl[k]);
                double ov = bv[k]; int ol = bl[k];
                if (better) { bv[k] = cv; bl[k] = cl; cv = ov; cl = ol; }
            }
        }
        int src = ordR[r];
        float* outRow = out + ((size_t)b * NPTS + src) * NPTS;
#pragma unroll
        for (int k = 0; k < TOPK; ++k) {
            int dst = ordBase[bl[k]];          // chunk-local -> global
            outRow[dst] = (float)bv[k];        // (b,src,dst) provably unique: plain store
        }
    }
}

// ---------------- launch ----------------
extern "C" void kernel_launch(void* const* d_in, const int* in_sizes, int n_in,
                              void* d_out, int out_size, void* d_ws, size_t ws_size,
                              hipStream_t stream) {
    const float* pts = (const float*)d_in[0];   // [2,5000,128]
    const float* rot = (const float*)d_in[1];   // [128,100]
    float* out = (float*)d_out;                 // [2,5000,5000]

    double* na      = (double*)d_ws;                                   // 80000 B
    int*    bin_idx = (int*)((char*)d_ws + (size_t)BATCH * NPTS * 8);  // 40000 B
    int*    order   = (int*)((char*)d_ws + (size_t)BATCH * NPTS * 12); // 40000 B

    hipMemsetAsync(d_out, 0, (size_t)out_size * sizeof(float), stream);

    k_bins<<<(BATCH * NPTS + 255) / 256, 256, 0, stream>>>(pts, rot, bin_idx, na);
    k_sort<<<BATCH, 256, 0, stream>>>(bin_idx, order);
    k_chunks<<<BATCH * NBINS * NCT, 256, 0, stream>>>(pts, na, order, out);
}

// Round 3
// 357.829 us; speedup vs baseline: 1.0586x; 1.0586x over previous
//
#include <hip/hip_runtime.h>
#include <cfloat>
#include <math.h>

#define NPTS   5000
#define BATCH  2
#define DIM    128
#define NBINS  10
#define BINSZ  500
#define TOPK   5
#define ROTCOLS 100   // rotations stored [128, 100]; we use first NBINS/2 = 5

// ---------------- Kernel A: bin assignment + squared norms (fp64 acc) -----
__global__ void k_bins(const float* __restrict__ pts, const float* __restrict__ rot,
                       int* __restrict__ bin_idx, double* __restrict__ na) {
    __shared__ float rotL[DIM * 5];
    int tid = threadIdx.x;
    for (int f = tid; f < DIM * 5; f += blockDim.x)
        rotL[f] = rot[(f / 5) * ROTCOLS + (f % 5)];
    __syncthreads();

    int i = blockIdx.x * blockDim.x + tid;
    if (i >= BATCH * NPTS) return;

    double acc[5] = {0., 0., 0., 0., 0.};
    double sq = 0.;
    const float* p = pts + (size_t)i * DIM;
    for (int d = 0; d < DIM; ++d) {
        double v = (double)p[d];
        sq += v * v;
#pragma unroll
        for (int h = 0; h < 5; ++h) acc[h] += v * (double)rotL[d * 5 + h];
    }
    double best = acc[0]; int bc = 0;
#pragma unroll
    for (int c = 1; c < NBINS; ++c) {
        double v = (c < 5) ? acc[c] : -acc[c - 5];
        if (v > best) { best = v; bc = c; }
    }
    bin_idx[i] = bc;
    na[i] = sq;
}

// ---------------- Kernel B: stable counting sort (== stable argsort) ------
__global__ void k_sort(const int* __restrict__ bin_idx, int* __restrict__ order) {
    const int b = blockIdx.x;
    const int t = threadIdx.x;               // 256 threads
    const int NPT = (NPTS + 255) / 256;      // 20
    int start = t * NPT;
    int end   = min(NPTS, start + NPT);

    int cnt[NBINS];
#pragma unroll
    for (int c = 0; c < NBINS; ++c) cnt[c] = 0;
    for (int i = start; i < end; ++i) cnt[bin_idx[b * NPTS + i]]++;

    __shared__ int hist[NBINS * 256];        // bin-major: hist[c*256 + t]
#pragma unroll
    for (int c = 0; c < NBINS; ++c) hist[c * 256 + t] = cnt[c];
    __syncthreads();

    int base = t * NBINS;
    int s = 0;
#pragma unroll
    for (int k = 0; k < NBINS; ++k) s += hist[base + k];
    __shared__ int scan[256];
    scan[t] = s;
    __syncthreads();
    for (int off = 1; off < 256; off <<= 1) {
        int v = (t >= off) ? scan[t - off] : 0;
        __syncthreads();
        scan[t] += v;
        __syncthreads();
    }
    int run = scan[t] - s;
#pragma unroll
    for (int k = 0; k < NBINS; ++k) { int h = hist[base + k]; hist[base + k] = run; run += h; }
    __syncthreads();

    int ofs[NBINS];
#pragma unroll
    for (int c = 0; c < NBINS; ++c) ofs[c] = hist[c * 256 + t];
    for (int i = start; i < end; ++i) {
        int c = bin_idx[b * NPTS + i];
        order[b * NPTS + ofs[c]] = i;        // stable: bin-major, thread-major, index-major
        ofs[c]++;
    }
}

// ---------------- Kernel C: gram + top-5 + fused zero-fill/scatter --------
#define RT    32       // rows per block
#define NRT   16       // ceil(500/32)
#define CTILE 64       // cols per LDS tile
#define RSTR  132      // padded row stride in floats (2-way LDS aliasing only, free)
#define NCT   8        // ceil(500/64)
#define ROWQ  (NPTS/4) // 1250 float4 per output row

__launch_bounds__(256, 3)
__global__ void k_chunks(const float* __restrict__ pts, const double* __restrict__ na,
                         const int* __restrict__ order, float* __restrict__ out) {
    __shared__ float  rowP[RT * RSTR];
    __shared__ float  colP[CTILE * RSTR];
    __shared__ double naC[CTILE];
    __shared__ double naRs[RT];
    __shared__ int    ordR[RT];

    int blk   = blockIdx.x;
    int rt    = blk & (NRT - 1);
    int chunk = blk >> 4;          // 0..19
    int b     = chunk / NBINS;
    int c     = chunk % NBINS;
    int tid   = threadIdx.x;
    int row0  = rt * RT;
    int rowCount = min(RT, BINSZ - row0);   // 32, except last tile: 20

    const int*   ordBase = order + b * NPTS + c * BINSZ;
    const float* ptsB    = pts + (size_t)b * NPTS * DIM;

    // stage row points (gathered via order)
    for (int f = tid; f < rowCount * (DIM / 4); f += 256) {
        int r = f / (DIM / 4);
        int q = f % (DIM / 4);
        int g = ordBase[row0 + r];
        float4 v = *(const float4*)(ptsB + (size_t)g * DIM + q * 4);
        *(float4*)(&rowP[r * RSTR + q * 4]) = v;
    }
    if (tid < rowCount) {
        int g = ordBase[row0 + tid];
        ordR[tid] = g;
        naRs[tid] = na[b * NPTS + g];
    }
    __syncthreads();

    // fused zero-fill of this block's output rows (replaces 200MB memset dispatch);
    // stores drain during the gram phase; barriers below order them before scatter.
    {
        float4 z = make_float4(0.f, 0.f, 0.f, 0.f);
        int total = rowCount * ROWQ;
        for (int f = tid; f < total; f += 256) {
            int r = f / ROWQ;
            int q = f - r * ROWQ;
            float* outRow = out + ((size_t)b * NPTS + ordR[r]) * NPTS;
            *(float4*)(outRow + 4 * q) = z;
        }
    }

    int rg = tid >> 4;   // 0..15: rows rg, rg+16  (16 consecutive lanes share a row set)
    int cg = tid & 15;   // 0..15: cols cg + 16*jj

    double naRr[2];
#pragma unroll
    for (int ii = 0; ii < 2; ++ii) {
        int r = rg + 16 * ii;
        naRr[ii] = (r < rowCount) ? naRs[r] : 0.;
    }

    double tv[2][TOPK];
    int    tl[2][TOPK];
#pragma unroll
    for (int ii = 0; ii < 2; ++ii)
#pragma unroll
        for (int k = 0; k < TOPK; ++k) { tv[ii][k] = -DBL_MAX; tl[ii][k] = 0x7fffffff; }

    for (int ct = 0; ct < NCT; ++ct) {
        int col0 = ct * CTILE;
        int colCount = min(CTILE, BINSZ - col0);
        __syncthreads();   // previous tile's readers done before restage
        for (int f = tid; f < colCount * (DIM / 4); f += 256) {
            int j = f / (DIM / 4);
            int q = f % (DIM / 4);
            int g = ordBase[col0 + j];
            float4 v = *(const float4*)(ptsB + (size_t)g * DIM + q * 4);
            *(float4*)(&colP[j * RSTR + q * 4]) = v;
        }
        if (tid < colCount) {
            int g = ordBase[col0 + tid];
            naC[tid] = na[b * NPTS + g];
        }
        __syncthreads();

        double acc[2][4];
#pragma unroll
        for (int ii = 0; ii < 2; ++ii)
#pragma unroll
            for (int jj = 0; jj < 4; ++jj) acc[ii][jj] = 0.;

        const float4* rowP4 = (const float4*)rowP;
        const float4* colP4 = (const float4*)colP;
        for (int q = 0; q < DIM / 4; ++q) {
            float4 a[2], bb[4];
#pragma unroll
            for (int ii = 0; ii < 2; ++ii) a[ii] = rowP4[(rg + 16 * ii) * (RSTR / 4) + q];
#pragma unroll
            for (int jj = 0; jj < 4; ++jj) bb[jj] = colP4[(cg + 16 * jj) * (RSTR / 4) + q];
            double ad[2][4], bd[4][4];
#pragma unroll
            for (int ii = 0; ii < 2; ++ii) {
                ad[ii][0] = (double)a[ii].x; ad[ii][1] = (double)a[ii].y;
                ad[ii][2] = (double)a[ii].z; ad[ii][3] = (double)a[ii].w;
            }
#pragma unroll
            for (int jj = 0; jj < 4; ++jj) {
                bd[jj][0] = (double)bb[jj].x; bd[jj][1] = (double)bb[jj].y;
                bd[jj][2] = (double)bb[jj].z; bd[jj][3] = (double)bb[jj].w;
            }
#pragma unroll
            for (int ii = 0; ii < 2; ++ii)
#pragma unroll
                for (int jj = 0; jj < 4; ++jj)
                    acc[ii][jj] += ad[ii][0] * bd[jj][0] + ad[ii][1] * bd[jj][1]
                                 + ad[ii][2] * bd[jj][2] + ad[ii][3] * bd[jj][3];
        }

        // dm + per-thread running top-5 (candidates arrive in increasing local idx)
#pragma unroll
        for (int jj = 0; jj < 4; ++jj) {
            int j = cg + 16 * jj;
            if (j < colCount) {
                int lc = col0 + j;
                double nc = naC[j];
#pragma unroll
                for (int ii = 0; ii < 2; ++ii) {
                    double d2   = naRr[ii] + nc - 2. * acc[ii][jj];
                    double dist = sqrt(fmax(d2, 1e-6));
                    double cv   = exp(-0.1 * dist);
                    int    cl   = lc;
#pragma unroll
                    for (int k = 0; k < TOPK; ++k) {   // strict > : equal keeps earlier idx
                        bool gt = (cv > tv[ii][k]);
                        double ov = tv[ii][k]; int ol = tl[ii][k];
                        if (gt) { tv[ii][k] = cv; tl[ii][k] = cl; cv = ov; cl = ol; }
                    }
                }
            }
        }
    }

    // merge across the 16 column-threads of each row via in-wave butterfly
    // (threads sharing a row are 16 consecutive lanes: lane = (rg%4)*16 + cg)
#pragma unroll
    for (int m = 1; m < 16; m <<= 1) {
#pragma unroll
        for (int ii = 0; ii < 2; ++ii) {
            double rv[TOPK]; int rl[TOPK];
#pragma unroll
            for (int k = 0; k < TOPK; ++k) {
                rv[k] = __shfl_xor(tv[ii][k], m, 16);
                rl[k] = __shfl_xor(tl[ii][k], m, 16);
            }
#pragma unroll
            for (int k = 0; k < TOPK; ++k) {
                double cv = rv[k]; int cl = rl[k];
#pragma unroll
                for (int s = 0; s < TOPK; ++s) {   // (val desc, idx asc) total order
                    bool better = (cv > tv[ii][s]) || (cv == tv[ii][s] && cl < tl[ii][s]);
                    double ov = tv[ii][s]; int ol = tl[ii][s];
                    if (better) { tv[ii][s] = cv; tl[ii][s] = cl; cv = ov; cl = ol; }
                }
            }
        }
    }

    // scatter: one thread per row writes its 5 values (zero-fill already drained
    // by the >=16 __syncthreads barriers above, each with vmcnt(0))
    if (cg == 0) {
#pragma unroll
        for (int ii = 0; ii < 2; ++ii) {
            int r = rg + 16 * ii;
            if (r < rowCount) {
                int src = ordR[r];
                float* outRow = out + ((size_t)b * NPTS + src) * NPTS;
#pragma unroll
                for (int k = 0; k < TOPK; ++k) {
                    int dst = ordBase[tl[ii][k]];  // chunk-local -> global
                    outRow[dst] = (float)tv[ii][k];
                }
            }
        }
    }
}

// ---------------- launch ----------------
extern "C" void kernel_launch(void* const* d_in, const int* in_sizes, int n_in,
                              void* d_out, int out_size, void* d_ws, size_t ws_size,
                              hipStream_t stream) {
    const float* pts = (const float*)d_in[0];   // [2,5000,128]
    const float* rot = (const float*)d_in[1];   // [128,100]
    float* out = (float*)d_out;                 // [2,5000,5000]

    double* na      = (double*)d_ws;                                   // 80000 B
    int*    bin_idx = (int*)((char*)d_ws + (size_t)BATCH * NPTS * 8);  // 40000 B
    int*    order   = (int*)((char*)d_ws + (size_t)BATCH * NPTS * 12); // 40000 B

    k_bins<<<(BATCH * NPTS + 255) / 256, 256, 0, stream>>>(pts, rot, bin_idx, na);
    k_sort<<<BATCH, 256, 0, stream>>>(bin_idx, order);
    k_chunks<<<BATCH * NBINS * NRT, 256, 0, stream>>>(pts, na, order, out);
}

// Round 4
// 328.127 us; speedup vs baseline: 1.1544x; 1.0905x over previous
//
#include <hip/hip_runtime.h>
#include <cfloat>
#include <math.h>

#define NPTS   5000
#define BATCH  2
#define DIM    128
#define NBINS  10
#define BINSZ  500
#define TOPK   5
#define ROTCOLS 100   // rotations stored [128, 100]; we use first NBINS/2 = 5

// ---------------- Kernel A: bin assignment + squared norms (fp64 acc) -----
// 64 points/block; coalesced global->LDS stage; 4 threads per point; shfl reduce.
#define KB_PTS 64
#define KB_STR 129    // pad: stride 129 floats
__global__ void k_bins(const float* __restrict__ pts, const float* __restrict__ rot,
                       int* __restrict__ bin_idx, double* __restrict__ na) {
    __shared__ float P[KB_PTS * KB_STR];
    __shared__ float rotL[DIM * 5];
    int tid = threadIdx.x;
    for (int f = tid; f < DIM * 5; f += 256)
        rotL[f] = rot[(f / 5) * ROTCOLS + (f % 5)];

    int p0  = blockIdx.x * KB_PTS;
    int npb = min(KB_PTS, BATCH * NPTS - p0);

    // coalesced stage: consecutive threads read consecutive floats of a row
    for (int f = tid; f < npb * DIM; f += 256) {
        int r = f >> 7, d = f & 127;
        P[r * KB_STR + d] = pts[(size_t)(p0 + r) * DIM + d];
    }
    __syncthreads();

    int p = tid >> 2;    // 0..63: point within block
    int s = tid & 3;     // 0..3 : dim quarter
    double acc[5] = {0., 0., 0., 0., 0.};
    double sq = 0.;
    const float* row = &P[p * KB_STR + s * 32];
    for (int j = 0; j < 32; ++j) {
        double v = (double)row[j];
        sq += v * v;
        int d = s * 32 + j;
#pragma unroll
        for (int h = 0; h < 5; ++h) acc[h] += v * (double)rotL[d * 5 + h];
    }
    // reduce over the 4 dim-quarters (consecutive lanes p*4+s)
#pragma unroll
    for (int m = 1; m < 4; m <<= 1) {
#pragma unroll
        for (int h = 0; h < 5; ++h) acc[h] += __shfl_xor(acc[h], m, 4);
        sq += __shfl_xor(sq, m, 4);
    }
    if (s == 0 && p < npb) {
        double best = acc[0]; int bc = 0;
#pragma unroll
        for (int c = 1; c < NBINS; ++c) {
            double v = (c < 5) ? acc[c] : -acc[c - 5];
            if (v > best) { best = v; bc = c; }
        }
        bin_idx[p0 + p] = bc;
        na[p0 + p] = sq;
    }
}

// ---------------- Kernel B: stable counting sort (== stable argsort) ------
__global__ void k_sort(const int* __restrict__ bin_idx, int* __restrict__ order) {
    const int b = blockIdx.x;
    const int t = threadIdx.x;               // 256 threads
    const int NPT = (NPTS + 255) / 256;      // 20
    int start = t * NPT;
    int end   = min(NPTS, start + NPT);

    int cnt[NBINS];
#pragma unroll
    for (int c = 0; c < NBINS; ++c) cnt[c] = 0;
    for (int i = start; i < end; ++i) {
        int c = bin_idx[b * NPTS + i];
#pragma unroll
        for (int k = 0; k < NBINS; ++k) cnt[k] += (c == k);   // static idx -> VGPRs
    }

    __shared__ int hist[NBINS * 256];        // bin-major: hist[c*256 + t]
#pragma unroll
    for (int c = 0; c < NBINS; ++c) hist[c * 256 + t] = cnt[c];
    __syncthreads();

    int base = t * NBINS;
    int s = 0;
#pragma unroll
    for (int k = 0; k < NBINS; ++k) s += hist[base + k];
    __shared__ int scan[256];
    scan[t] = s;
    __syncthreads();
    for (int off = 1; off < 256; off <<= 1) {
        int v = (t >= off) ? scan[t - off] : 0;
        __syncthreads();
        scan[t] += v;
        __syncthreads();
    }
    int run = scan[t] - s;
#pragma unroll
    for (int k = 0; k < NBINS; ++k) { int h = hist[base + k]; hist[base + k] = run; run += h; }
    __syncthreads();

    int ofs[NBINS];
#pragma unroll
    for (int c = 0; c < NBINS; ++c) ofs[c] = hist[c * 256 + t];
    for (int i = start; i < end; ++i) {
        int c = bin_idx[b * NPTS + i];
        int pos = 0;
#pragma unroll
        for (int k = 0; k < NBINS; ++k) {                      // static idx -> VGPRs
            if (c == k) pos = ofs[k];
            ofs[k] += (c == k);
        }
        order[b * NPTS + pos] = i;           // stable: bin-major, thread-major, index-major
    }
}

// ---------------- Kernel C: gram + top-5 + fused zero-fill/scatter --------
#define RT    16       // rows per block
#define NRT   32       // ceil(500/16) = 32 (last tile: 4 rows)
#define CTILE 64       // cols per LDS tile
#define RSTR  132      // padded row stride in floats (2-way LDS aliasing only, free)
#define NCT   8        // ceil(500/64)
#define ROWQ  (NPTS/4) // 1250 float4 per output row

__launch_bounds__(256, 3)
__global__ void k_chunks(const float* __restrict__ pts, const double* __restrict__ na,
                         const int* __restrict__ order, float* __restrict__ out) {
    __shared__ float  rowP[RT * RSTR];
    __shared__ float  colP[CTILE * RSTR];
    __shared__ double naC[CTILE];
    __shared__ double naRs[RT];
    __shared__ int    ordR[RT];

    int blk   = blockIdx.x;
    int rt    = blk & (NRT - 1);
    int chunk = blk >> 5;          // 0..19
    int b     = chunk / NBINS;
    int c     = chunk % NBINS;
    int tid   = threadIdx.x;
    int row0  = rt * RT;
    int rowCount = min(RT, BINSZ - row0);   // 16, except last tile: 4

    const int*   ordBase = order + b * NPTS + c * BINSZ;
    const float* ptsB    = pts + (size_t)b * NPTS * DIM;

    // stage row points (gathered via order)
    for (int f = tid; f < rowCount * (DIM / 4); f += 256) {
        int r = f / (DIM / 4);
        int q = f % (DIM / 4);
        int g = ordBase[row0 + r];
        float4 v = *(const float4*)(ptsB + (size_t)g * DIM + q * 4);
        *(float4*)(&rowP[r * RSTR + q * 4]) = v;
    }
    if (tid < rowCount) {
        int g = ordBase[row0 + tid];
        ordR[tid] = g;
        naRs[tid] = na[b * NPTS + g];
    }
    __syncthreads();

    // fused zero-fill of this block's output rows; stores drain during gram,
    // ordered before the scatter by the __syncthreads (vmcnt(0)) below.
    {
        float4 z = make_float4(0.f, 0.f, 0.f, 0.f);
        int total = rowCount * ROWQ;
        for (int f = tid; f < total; f += 256) {
            int r = f / ROWQ;
            int q = f - r * ROWQ;
            float* outRow = out + ((size_t)b * NPTS + ordR[r]) * NPTS;
            *(float4*)(outRow + 4 * q) = z;
        }
    }

    int rg = tid >> 4;   // 0..15: this thread's row
    int cg = tid & 15;   // cols cg + 16*jj

    double naRr = (rg < rowCount) ? naRs[rg] : 0.;

    double tv[TOPK];
    int    tl[TOPK];
#pragma unroll
    for (int k = 0; k < TOPK; ++k) { tv[k] = -DBL_MAX; tl[k] = 0x7fffffff; }

    for (int ct = 0; ct < NCT; ++ct) {
        int col0 = ct * CTILE;
        int colCount = min(CTILE, BINSZ - col0);
        __syncthreads();   // previous tile's readers done before restage
        for (int f = tid; f < colCount * (DIM / 4); f += 256) {
            int j = f / (DIM / 4);
            int q = f % (DIM / 4);
            int g = ordBase[col0 + j];
            float4 v = *(const float4*)(ptsB + (size_t)g * DIM + q * 4);
            *(float4*)(&colP[j * RSTR + q * 4]) = v;
        }
        if (tid < colCount) {
            int g = ordBase[col0 + tid];
            naC[tid] = na[b * NPTS + g];
        }
        __syncthreads();

        double acc[4];
#pragma unroll
        for (int jj = 0; jj < 4; ++jj) acc[jj] = 0.;

        const float4* rowP4 = (const float4*)(rowP);
        const float4* colP4 = (const float4*)(colP);
        for (int q = 0; q < DIM / 4; ++q) {
            float4 a = rowP4[rg * (RSTR / 4) + q];
            float4 bb[4];
#pragma unroll
            for (int jj = 0; jj < 4; ++jj) bb[jj] = colP4[(cg + 16 * jj) * (RSTR / 4) + q];
            double ad[4];
            ad[0] = (double)a.x; ad[1] = (double)a.y; ad[2] = (double)a.z; ad[3] = (double)a.w;
#pragma unroll
            for (int jj = 0; jj < 4; ++jj) {
                acc[jj] += ad[0] * (double)bb[jj].x + ad[1] * (double)bb[jj].y
                         + ad[2] * (double)bb[jj].z + ad[3] * (double)bb[jj].w;
            }
        }

        // dm + per-thread running top-5 (candidates arrive in increasing local idx)
#pragma unroll
        for (int jj = 0; jj < 4; ++jj) {
            int j = cg + 16 * jj;
            if (j < colCount) {
                int lc = col0 + j;
                double nc = naC[j];
                double d2   = naRr + nc - 2. * acc[jj];
                double dist = sqrt(fmax(d2, 1e-6));
                double cv   = exp(-0.1 * dist);
                int    cl   = lc;
#pragma unroll
                for (int k = 0; k < TOPK; ++k) {   // strict > : equal keeps earlier idx
                    bool gt = (cv > tv[k]);
                    double ov = tv[k]; int ol = tl[k];
                    if (gt) { tv[k] = cv; tl[k] = cl; cv = ov; cl = ol; }
                }
            }
        }
    }

    // merge across the 16 column-threads of each row via in-wave butterfly
    // (threads sharing a row are 16 consecutive lanes)
#pragma unroll
    for (int m = 1; m < 16; m <<= 1) {
        double rv[TOPK]; int rl[TOPK];
#pragma unroll
        for (int k = 0; k < TOPK; ++k) {
            rv[k] = __shfl_xor(tv[k], m, 16);
            rl[k] = __shfl_xor(tl[k], m, 16);
        }
#pragma unroll
        for (int k = 0; k < TOPK; ++k) {
            double cv = rv[k]; int cl = rl[k];
#pragma unroll
            for (int s = 0; s < TOPK; ++s) {   // (val desc, idx asc) total order
                bool better = (cv > tv[s]) || (cv == tv[s] && cl < tl[s]);
                double ov = tv[s]; int ol = tl[s];
                if (better) { tv[s] = cv; tl[s] = cl; cv = ov; cl = ol; }
            }
        }
    }

    // scatter: one thread per row writes its 5 values
    if (cg == 0 && rg < rowCount) {
        int src = ordR[rg];
        float* outRow = out + ((size_t)b * NPTS + src) * NPTS;
#pragma unroll
        for (int k = 0; k < TOPK; ++k) {
            int dst = ordBase[tl[k]];          // chunk-local -> global
            outRow[dst] = (float)tv[k];
        }
    }
}

// ---------------- launch ----------------
extern "C" void kernel_launch(void* const* d_in, const int* in_sizes, int n_in,
                              void* d_out, int out_size, void* d_ws, size_t ws_size,
                              hipStream_t stream) {
    const float* pts = (const float*)d_in[0];   // [2,5000,128]
    const float* rot = (const float*)d_in[1];   // [128,100]
    float* out = (float*)d_out;                 // [2,5000,5000]

    double* na      = (double*)d_ws;                                   // 80000 B
    int*    bin_idx = (int*)((char*)d_ws + (size_t)BATCH * NPTS * 8);  // 40000 B
    int*    order   = (int*)((char*)d_ws + (size_t)BATCH * NPTS * 12); // 40000 B

    k_bins<<<(BATCH * NPTS + KB_PTS - 1) / KB_PTS, 256, 0, stream>>>(pts, rot, bin_idx, na);
    k_sort<<<BATCH, 256, 0, stream>>>(bin_idx, order);
    k_chunks<<<BATCH * NBINS * NRT, 256, 0, stream>>>(pts, na, order, out);
}

// Round 5
// 302.426 us; speedup vs baseline: 1.2525x; 1.0850x over previous
//
#include <hip/hip_runtime.h>
#include <cfloat>
#include <math.h>

#define NPTS   5000
#define BATCH  2
#define DIM    128
#define NBINS  10
#define BINSZ  500
#define TOPK   5
#define ROTCOLS 100   // rotations stored [128, 100]; we use first NBINS/2 = 5

// ---------------- Kernel A: bin assignment + squared norms (fp64 acc) -----
// 64 points/block; coalesced global->LDS stage; 4 threads per point; shfl reduce.
#define KB_PTS 64
#define KB_STR 129    // pad: stride 129 floats
__global__ void k_bins(const float* __restrict__ pts, const float* __restrict__ rot,
                       int* __restrict__ bin_idx, double* __restrict__ na) {
    __shared__ float P[KB_PTS * KB_STR];
    __shared__ float rotL[DIM * 5];
    int tid = threadIdx.x;
    for (int f = tid; f < DIM * 5; f += 256)
        rotL[f] = rot[(f / 5) * ROTCOLS + (f % 5)];

    int p0  = blockIdx.x * KB_PTS;
    int npb = min(KB_PTS, BATCH * NPTS - p0);

    for (int f = tid; f < npb * DIM; f += 256) {
        int r = f >> 7, d = f & 127;
        P[r * KB_STR + d] = pts[(size_t)(p0 + r) * DIM + d];
    }
    __syncthreads();

    int p = tid >> 2;    // 0..63: point within block
    int s = tid & 3;     // 0..3 : dim quarter
    double acc[5] = {0., 0., 0., 0., 0.};
    double sq = 0.;
    const float* row = &P[p * KB_STR + s * 32];
    for (int j = 0; j < 32; ++j) {
        double v = (double)row[j];
        sq += v * v;
        int d = s * 32 + j;
#pragma unroll
        for (int h = 0; h < 5; ++h) acc[h] += v * (double)rotL[d * 5 + h];
    }
#pragma unroll
    for (int m = 1; m < 4; m <<= 1) {
#pragma unroll
        for (int h = 0; h < 5; ++h) acc[h] += __shfl_xor(acc[h], m, 4);
        sq += __shfl_xor(sq, m, 4);
    }
    if (s == 0 && p < npb) {
        double best = acc[0]; int bc = 0;
#pragma unroll
        for (int c = 1; c < NBINS; ++c) {
            double v = (c < 5) ? acc[c] : -acc[c - 5];
            if (v > best) { best = v; bc = c; }
        }
        bin_idx[p0 + p] = bc;
        na[p0 + p] = sq;
    }
}

// ---------------- Kernel B: stable counting sort (== stable argsort) ------
__global__ void k_sort(const int* __restrict__ bin_idx, int* __restrict__ order) {
    const int b = blockIdx.x;
    const int t = threadIdx.x;               // 256 threads
    const int NPT = (NPTS + 255) / 256;      // 20
    int start = t * NPT;
    int end   = min(NPTS, start + NPT);

    int cnt[NBINS];
#pragma unroll
    for (int c = 0; c < NBINS; ++c) cnt[c] = 0;
    for (int i = start; i < end; ++i) {
        int c = bin_idx[b * NPTS + i];
#pragma unroll
        for (int k = 0; k < NBINS; ++k) cnt[k] += (c == k);   // static idx -> VGPRs
    }

    __shared__ int hist[NBINS * 256];        // bin-major: hist[c*256 + t]
#pragma unroll
    for (int c = 0; c < NBINS; ++c) hist[c * 256 + t] = cnt[c];
    __syncthreads();

    int base = t * NBINS;
    int s = 0;
#pragma unroll
    for (int k = 0; k < NBINS; ++k) s += hist[base + k];
    __shared__ int scan[256];
    scan[t] = s;
    __syncthreads();
    for (int off = 1; off < 256; off <<= 1) {
        int v = (t >= off) ? scan[t - off] : 0;
        __syncthreads();
        scan[t] += v;
        __syncthreads();
    }
    int run = scan[t] - s;
#pragma unroll
    for (int k = 0; k < NBINS; ++k) { int h = hist[base + k]; hist[base + k] = run; run += h; }
    __syncthreads();

    int ofs[NBINS];
#pragma unroll
    for (int c = 0; c < NBINS; ++c) ofs[c] = hist[c * 256 + t];
    for (int i = start; i < end; ++i) {
        int c = bin_idx[b * NPTS + i];
        int pos = 0;
#pragma unroll
        for (int k = 0; k < NBINS; ++k) {
            if (c == k) pos = ofs[k];
            ofs[k] += (c == k);
        }
        order[b * NPTS + pos] = i;           // stable: bin-major, thread-major, index-major
    }
}

// ---------------- Kernel C: gram + top-5 + interleaved zero-fill/scatter --
#define RT    16       // rows per block
#define NRT   32       // ceil(500/16)
#define CTILE 64       // cols per LDS tile
#define RSTR  132      // padded row stride (2-way LDS aliasing only, free)
#define NCT   8        // 500 / 64 (ceil)
#define ROWQ  (NPTS/4) // 1250 float4 per output row

__launch_bounds__(256, 3)
__global__ void k_chunks(const float* __restrict__ pts, const double* __restrict__ na,
                         const int* __restrict__ order, float* __restrict__ out) {
    __shared__ float  rowP[RT * RSTR];
    __shared__ float  colP[CTILE * RSTR];
    __shared__ double naC[CTILE];
    __shared__ double naRs[RT];
    __shared__ int    ordR[RT];

    int blk   = blockIdx.x;
    int rt    = blk & (NRT - 1);
    int chunk = blk >> 5;          // 0..19
    int b     = chunk / NBINS;
    int c     = chunk % NBINS;
    int tid   = threadIdx.x;
    int row0  = rt * RT;
    int rowCount = min(RT, BINSZ - row0);   // 16, except last tile: 4

    const int*   ordBase = order + b * NPTS + c * BINSZ;
    const float* ptsB    = pts + (size_t)b * NPTS * DIM;

    // stage row points (gathered via order)
    for (int f = tid; f < rowCount * (DIM / 4); f += 256) {
        int r = f / (DIM / 4);
        int q = f % (DIM / 4);
        int g = ordBase[row0 + r];
        float4 v = *(const float4*)(ptsB + (size_t)g * DIM + q * 4);
        *(float4*)(&rowP[r * RSTR + q * 4]) = v;
    }
    if (tid < rowCount) {
        int g = ordBase[row0 + tid];
        ordR[tid] = g;
        naRs[tid] = na[b * NPTS + g];
    }
    __syncthreads();

    int rg = tid >> 4;   // 0..15: this thread's row
    int cg = tid & 15;   // cols cg + 16*jj

    double naRr = (rg < rowCount) ? naRs[rg] : 0.;

    // selection key: clamped squared distance (smaller = better). dm is a
    // strictly decreasing function of this key, so top-5 dm == bottom-5 key,
    // with identical tie semantics (lower index wins).
    double tv[TOPK];
    int    tl[TOPK];
#pragma unroll
    for (int k = 0; k < TOPK; ++k) { tv[k] = DBL_MAX; tl[k] = 0x7fffffff; }

    const int totalZ = rowCount * ROWQ;      // float4 zero-stores this block owns

    for (int ct = 0; ct < NCT; ++ct) {
        int col0 = ct * CTILE;
        int colCount = min(CTILE, BINSZ - col0);
        __syncthreads();   // prev tile's readers done (also drains prev zero slice)
        for (int f = tid; f < colCount * (DIM / 4); f += 256) {
            int j = f / (DIM / 4);
            int q = f % (DIM / 4);
            int g = ordBase[col0 + j];
            float4 v = *(const float4*)(ptsB + (size_t)g * DIM + q * 4);
            *(float4*)(&colP[j * RSTR + q * 4]) = v;
        }
        if (tid < colCount) {
            int g = ordBase[col0 + tid];
            naC[tid] = na[b * NPTS + g];
        }
        __syncthreads();

        // zero-fill slice ct: stores drain during this tile's gram compute
        {
            float4 z = make_float4(0.f, 0.f, 0.f, 0.f);
            int z0 = (ct * totalZ) / NCT, z1 = ((ct + 1) * totalZ) / NCT;
            for (int f = z0 + tid; f < z1; f += 256) {
                int r = f / ROWQ;
                int q = f - r * ROWQ;
                float* outRow = out + ((size_t)b * NPTS + ordR[r]) * NPTS;
                *(float4*)(outRow + 4 * q) = z;
            }
        }

        double acc[4];
#pragma unroll
        for (int jj = 0; jj < 4; ++jj) acc[jj] = 0.;

        const float4* rowP4 = (const float4*)(rowP);
        const float4* colP4 = (const float4*)(colP);
        for (int q = 0; q < DIM / 4; ++q) {
            float4 a = rowP4[rg * (RSTR / 4) + q];
            float4 bb[4];
#pragma unroll
            for (int jj = 0; jj < 4; ++jj) bb[jj] = colP4[(cg + 16 * jj) * (RSTR / 4) + q];
            double ad[4];
            ad[0] = (double)a.x; ad[1] = (double)a.y; ad[2] = (double)a.z; ad[3] = (double)a.w;
#pragma unroll
            for (int jj = 0; jj < 4; ++jj) {
                acc[jj] += ad[0] * (double)bb[jj].x + ad[1] * (double)bb[jj].y
                         + ad[2] * (double)bb[jj].z + ad[3] * (double)bb[jj].w;
            }
        }

        // running bottom-5 of clamped d2 (candidates arrive in increasing idx)
#pragma unroll
        for (int jj = 0; jj < 4; ++jj) {
            int j = cg + 16 * jj;
            if (j < colCount) {
                int    cl = col0 + j;
                double cv = fmax(naRr + naC[j] - 2. * acc[jj], 1e-6);
#pragma unroll
                for (int k = 0; k < TOPK; ++k) {   // strict < : equal keeps earlier idx
                    bool lt = (cv < tv[k]);
                    double ov = tv[k]; int ol = tl[k];
                    if (lt) { tv[k] = cv; tl[k] = cl; cv = ov; cl = ol; }
                }
            }
        }
    }

    // merge across the 16 column-threads of each row via in-wave butterfly
#pragma unroll
    for (int m = 1; m < 16; m <<= 1) {
        double rv[TOPK]; int rl[TOPK];
#pragma unroll
        for (int k = 0; k < TOPK; ++k) {
            rv[k] = __shfl_xor(tv[k], m, 16);
            rl[k] = __shfl_xor(tl[k], m, 16);
        }
#pragma unroll
        for (int k = 0; k < TOPK; ++k) {
            double cv = rv[k]; int cl = rl[k];
#pragma unroll
            for (int s = 0; s < TOPK; ++s) {   // (key asc, idx asc) total order
                bool better = (cv < tv[s]) || (cv == tv[s] && cl < tl[s]);
                double ov = tv[s]; int ol = tl[s];
                if (better) { tv[s] = cv; tl[s] = cl; cv = ov; cl = ol; }
            }
        }
    }

    __syncthreads();   // drain last zero slice before scatter (order zeros < values)

    // scatter: one thread per row computes dm for its 5 winners and writes
    if (cg == 0 && rg < rowCount) {
        int src = ordR[rg];
        float* outRow = out + ((size_t)b * NPTS + src) * NPTS;
#pragma unroll
        for (int k = 0; k < TOPK; ++k) {
            double dist = sqrt(tv[k]);            // tv already clamped
            double dm   = exp(-0.1 * dist);
            int dst = ordBase[tl[k]];             // chunk-local -> global
            outRow[dst] = (float)dm;
        }
    }
}

// ---------------- launch ----------------
extern "C" void kernel_launch(void* const* d_in, const int* in_sizes, int n_in,
                              void* d_out, int out_size, void* d_ws, size_t ws_size,
                              hipStream_t stream) {
    const float* pts = (const float*)d_in[0];   // [2,5000,128]
    const float* rot = (const float*)d_in[1];   // [128,100]
    float* out = (float*)d_out;                 // [2,5000,5000]

    double* na      = (double*)d_ws;                                   // 80000 B
    int*    bin_idx = (int*)((char*)d_ws + (size_t)BATCH * NPTS * 8);  // 40000 B
    int*    order   = (int*)((char*)d_ws + (size_t)BATCH * NPTS * 12); // 40000 B

    k_bins<<<(BATCH * NPTS + KB_PTS - 1) / KB_PTS, 256, 0, stream>>>(pts, rot, bin_idx, na);
    k_sort<<<BATCH, 256, 0, stream>>>(bin_idx, order);
    k_chunks<<<BATCH * NBINS * NRT, 256, 0, stream>>>(pts, na, order, out);
}